// Round 4
// baseline (5391.540 us; speedup 1.0000x reference)
//
#include <hip/hip_runtime.h>
#include <stdint.h>

typedef __attribute__((ext_vector_type(8))) short bf16x8;
typedef __attribute__((ext_vector_type(4))) float f32x4;
typedef __attribute__((ext_vector_type(2))) unsigned long long u64x2;

__device__ __forceinline__ float bf2f(unsigned short u) {
    union { unsigned int u32; float f; } v; v.u32 = ((unsigned int)u) << 16; return v.f;
}
__device__ __forceinline__ unsigned short f2bf(float f) {
    union { float f; unsigned int u32; } v; v.f = f;
    unsigned int r = v.u32 + 0x7FFFu + ((v.u32 >> 16) & 1u);
    return (unsigned short)(r >> 16);
}
__device__ __forceinline__ float sigm(float x) { return 1.f / (1.f + __expf(-x)); }
__device__ __forceinline__ float tanh_fast(float x) {
    float ax = fabsf(x);
    float e = __expf(-2.f * ax);
    float t = (1.f - e) / (1.f + e);
    return copysignf(t, x);
}

// ---------------- fp32 -> bf16 convert (n4 = count of float4 groups) -------------
__global__ void f2bf_kernel(const float* __restrict__ src, unsigned short* __restrict__ dst, int n4) {
    int i = blockIdx.x * blockDim.x + threadIdx.x;
    if (i >= n4) return;
    float4 v = ((const float4*)src)[i];
    ushort4 o;
    o.x = f2bf(v.x); o.y = f2bf(v.y); o.z = f2bf(v.z); o.w = f2bf(v.w);
    ((ushort4*)dst)[i] = o;
}

// ---------------- combined bias: [2048] = fwd(bih+bhh) | rev(bih+bhh) ------------
__global__ void bias_comb_kernel(const float* __restrict__ bif, const float* __restrict__ bhf,
                                 const float* __restrict__ bir, const float* __restrict__ bhr,
                                 float* __restrict__ out) {
    int n = blockIdx.x * blockDim.x + threadIdx.x;
    if (n >= 2048) return;
    out[n] = (n < 1024) ? (bif[n] + bhf[n]) : (bir[n - 1024] + bhr[n - 1024]);
}

// ---------------- GEMM: C[m,n](bf16) = sum_k A[m,k]*B[n,k] + bias[n] -------------
__global__ __launch_bounds__(256, 2) void gemm_bt_bias(
    const unsigned short* __restrict__ A, const unsigned short* __restrict__ B,
    const float* __restrict__ bias, unsigned short* __restrict__ C,
    int M, int N, int K) {
    const int bn0 = blockIdx.x * 128;
    const int bm0 = blockIdx.y * 128;
    const int tid = threadIdx.x;
    const int wave = tid >> 6, lane = tid & 63;
    const int ln15 = lane & 15, quad = lane >> 4;
    const int wr = wave >> 1, wc = wave & 1;

    __shared__ __align__(16) unsigned short At[128 * 72];
    __shared__ __align__(16) unsigned short Bt[128 * 72];

    f32x4 acc[4][4] = {};

    for (int ko = 0; ko < K; ko += 64) {
#pragma unroll
        for (int i = 0; i < 4; ++i) {
            int chunk = tid + i * 256;
            int row = chunk >> 3, cc = chunk & 7;
            *(bf16x8*)&At[row * 72 + cc * 8] = *(const bf16x8*)&A[(size_t)(bm0 + row) * K + ko + cc * 8];
            *(bf16x8*)&Bt[row * 72 + cc * 8] = *(const bf16x8*)&B[(size_t)(bn0 + row) * K + ko + cc * 8];
        }
        __syncthreads();
#pragma unroll
        for (int kk = 0; kk < 2; ++kk) {
            bf16x8 a[4], b[4];
#pragma unroll
            for (int f = 0; f < 4; ++f) {
                a[f] = *(const bf16x8*)&At[(wr * 64 + f * 16 + ln15) * 72 + kk * 32 + quad * 8];
                b[f] = *(const bf16x8*)&Bt[(wc * 64 + f * 16 + ln15) * 72 + kk * 32 + quad * 8];
            }
#pragma unroll
            for (int fi = 0; fi < 4; ++fi)
#pragma unroll
                for (int fj = 0; fj < 4; ++fj)
                    acc[fi][fj] = __builtin_amdgcn_mfma_f32_16x16x32_bf16(a[fi], b[fj], acc[fi][fj], 0, 0, 0);
        }
        __syncthreads();
    }
#pragma unroll
    for (int fi = 0; fi < 4; ++fi) {
        int row = bm0 + wr * 64 + fi * 16 + quad * 4;
#pragma unroll
        for (int fj = 0; fj < 4; ++fj) {
            int col = bn0 + wc * 64 + fj * 16 + ln15;
            float bv = bias[col];
#pragma unroll
            for (int r = 0; r < 4; ++r)
                C[(size_t)(row + r) * N + col] = f2bf(acc[fi][fj][r] + bv);
        }
    }
}

// ================= persistent LSTM scan v7: mechanism-verified dual path =========
// 128 WGs: gid = b&31 (group: dir=gid&1, bg=gid>>1), cg = b>>5 (64 hidden cols).
// Ring: hexg[8][2][16][16 rows][64 colgroups] u64 (4x bf16). Sentinel ~0ull
// (4x bf16 -NaN, impossible for |h|<1): the data IS the ready signal.
//
// CERTIFICATION: one __syncthreads between spin-exit and publish. Observing a
// slot-s word from WG Y proves Y's whole WG exited its spin on slot s-1; a
// consumer's 16 spin words span all 4 group WGs, so passing the spin on s
// certifies all 4 WGs consumed s-1 -> poisoning s-1 afterwards is race-free.
// Poison-before-republish (same thread+address, 6 steps later) is ordered by
// the vmcnt(0) drains every spin poll performs.
//
// FAST (sc0-only, same-L2 exchange) is gated by a MECHANISM handshake, not
// topology inference: phase A stores/spins MAGIC1 via sc0 (caches canaries),
// an agent-scope sync separates phases, phase B stores MAGIC2 and must OBSERVE
// THE CHANGE through the same path -- stale-L1 or cross-XCD configurations
// provably time out -> SLOW. The verdict is exchanged via agent-scope ops and
// ANDed across the group -> all 4 members take the same path (no mixed mode).
// Groups are independent (disjoint 8KB slabs; no cache-line sharing).
__device__ __forceinline__ void st1_sc0(unsigned long long* p, unsigned long long v) {
    asm volatile("global_store_dwordx2 %0, %1, off sc0" :: "v"(p), "v"(v) : "memory");
}
__device__ __forceinline__ unsigned long long ld1_sc0(const unsigned long long* p) {
    unsigned long long v;
    asm volatile("global_load_dwordx2 %0, %1, off sc0\n\ts_waitcnt vmcnt(0)"
                 : "=v"(v) : "v"(p) : "memory");
    return v;
}

template<bool FAST>
__device__ void scan_loop(const unsigned short* __restrict__ xg,
                          const unsigned short* __restrict__ whh,
                          unsigned short* __restrict__ out_bf,
                          float* __restrict__ out_f,
                          unsigned long long* hex64, int dir, int bg, int cg)
{
    const int tid = threadIdx.x;
    const int wave = tid >> 6, lane = tid & 63;
    const int ln15 = lane & 15, quad = lane >> 4;
    const int m0 = bg * 16;
    const int rowr = quad * 4 + (ln15 & 3);                 // batch-local row this lane publishes
    const int colg = cg * 16 + wave * 4 + (ln15 >> 2);      // colgroup (hidden col / 4)
    const unsigned long long SENT = ~0ull;
    const unsigned long long M16 = 0x0000FFFF0000FFFFull;

    // ---- one-time: Whh fragments, gate-per-N-tile (N-tile g = gate g) ----
    bf16x8 Bfr[32];
#pragma unroll
    for (int kb = 0; kb < 8; ++kb)
#pragma unroll
        for (int g = 0; g < 4; ++g)
            Bfr[kb * 4 + g] = *(const bf16x8*)&whh[
                (size_t)(g * 256 + cg * 64 + wave * 16 + ln15) * 256 + kb * 32 + quad * 8];

    float c[4] = {0.f, 0.f, 0.f, 0.f};
    const unsigned short* xbase = xg + (size_t)(m0 + quad * 4) * 2048
                                     + dir * 1024 + cg * 64 + wave * 16 + ln15;

    unsigned short xvA[16], xvB[16];
    {   // prefetch xg for tt = 0
        const int t0 = dir ? 159 : 0;
        const unsigned short* xr = xbase + (size_t)t0 * 256 * 2048;
#pragma unroll
        for (int g = 0; g < 4; ++g)
#pragma unroll
            for (int r = 0; r < 4; ++r)
                xvA[g * 4 + r] = xr[(size_t)r * 2048 + g * 256];
    }

    auto step = [&](int tt, unsigned short (&xu)[16], unsigned short (&xp)[16]) {
        const int t = dir ? (159 - tt) : tt;

        // ---- spin on slot (tt-1)&7: detection load IS the A-operand load ----
        const int slot_r = (tt + 7) & 7;
        unsigned long long* hsrc = hex64 + ((size_t)(slot_r * 2 + dir) * 16 + bg) * 1024
                                 + ln15 * 64 + quad * 2;
        unsigned long long w[16];
        if (FAST) {
            u64x2 wv[8];
            int lim = 1 << 16;
            for (;;) {
#define RL(I, OFF) asm volatile("global_load_dwordx4 %0, %1, off offset:" OFF " sc0" : "=v"(wv[I]) : "v"(hsrc))
                RL(0, "0");  RL(1, "64");  RL(2, "128"); RL(3, "192");
                RL(4, "256"); RL(5, "320"); RL(6, "384"); RL(7, "448");
#undef RL
                asm volatile("s_waitcnt vmcnt(0)" ::: "memory");
                __builtin_amdgcn_sched_barrier(0);
                bool ok = true;
#pragma unroll
                for (int i = 0; i < 8; ++i) ok &= (wv[i][0] != SENT) & (wv[i][1] != SENT);
                if (ok || !--lim) break;
            }
#pragma unroll
            for (int i = 0; i < 8; ++i) { w[i * 2] = wv[i][0]; w[i * 2 + 1] = wv[i][1]; }
        } else {
            int lim = 1 << 17;
            for (;;) {
#pragma unroll
                for (int kb = 0; kb < 8; ++kb) {
                    w[kb * 2]     = __hip_atomic_load(hsrc + kb * 8,     __ATOMIC_RELAXED, __HIP_MEMORY_SCOPE_AGENT);
                    w[kb * 2 + 1] = __hip_atomic_load(hsrc + kb * 8 + 1, __ATOMIC_RELAXED, __HIP_MEMORY_SCOPE_AGENT);
                }
                bool ok = true;
#pragma unroll
                for (int i = 0; i < 16; ++i) ok &= (w[i] != SENT);
                if (ok || !--lim) break;
                __builtin_amdgcn_s_sleep(2);
            }
        }

        // ---- certification barrier: whole WG passed the spin before ANY publish ----
        __syncthreads();

        // ---- xg prefetch for NEXT step: issue now, latency hides under MFMA ----
        {
            const int ttn = (tt < 159) ? tt + 1 : tt;
            const int tn = dir ? (159 - ttn) : ttn;
            const unsigned short* xr = xbase + (size_t)tn * 256 * 2048;
#pragma unroll
            for (int g = 0; g < 4; ++g)
#pragma unroll
                for (int r = 0; r < 4; ++r)
                    xp[g * 4 + r] = xr[(size_t)r * 2048 + g * 256];
        }

        // ---- recurrent GEMM: 32 MFMAs, acc starts at 0 (xg added at activation) ----
        bf16x8 af[8];
#pragma unroll
        for (int kb = 0; kb < 8; ++kb) {
            union { unsigned long long u[2]; bf16x8 v; } tm;
            tm.u[0] = w[kb * 2]; tm.u[1] = w[kb * 2 + 1];
            af[kb] = tm.v;
        }
        f32x4 acc[4] = {};
#pragma unroll
        for (int kb = 0; kb < 8; ++kb)
#pragma unroll
            for (int g = 0; g < 4; ++g)
                acc[g] = __builtin_amdgcn_mfma_f32_16x16x32_bf16(af[kb], Bfr[kb * 4 + g], acc[g], 0, 0, 0);

        // ---- activations + cell update: all 4 gates thread-local ----
        float hv[4];
#pragma unroll
        for (int r = 0; r < 4; ++r) {
            float iv = sigm(acc[0][r] + bf2f(xu[0 + r]));
            float fv = sigm(acc[1][r] + bf2f(xu[4 + r]));
            float gv = tanh_fast(acc[2][r] + bf2f(xu[8 + r]));
            float ov = sigm(acc[3][r] + bf2f(xu[12 + r]));
            float cn = fv * c[r] + iv * gv;
            c[r] = cn;
            hv[r] = ov * tanh_fast(cn);
        }

        // ---- pack (col-major) + in-register 4x4 bf16 transpose -> row-major ----
        unsigned long long P = (unsigned long long)f2bf(hv[0])
                             | ((unsigned long long)f2bf(hv[1]) << 16)
                             | ((unsigned long long)f2bf(hv[2]) << 32)
                             | ((unsigned long long)f2bf(hv[3]) << 48);
        unsigned long long X = __shfl_xor(P, 2);
        unsigned long long Nn = (ln15 & 2) ? ((X >> 32) | (P & 0xFFFFFFFF00000000ull))
                                           : ((P & 0x00000000FFFFFFFFull) | (X << 32));
        unsigned long long Y = __shfl_xor(Nn, 1);
        unsigned long long Q = (ln15 & 1) ? (((Y >> 16) & M16) | (((Nn >> 16) & M16) << 16))
                                          : ((Nn & M16) | ((Y & M16) << 16));

        // ---- PUBLISH first (the critical outgoing edge) ----
        unsigned long long* hdst = hex64 + ((size_t)((tt & 7) * 2 + dir) * 16 + bg) * 1024
                                 + rowr * 64 + colg;
        if (FAST) st1_sc0(hdst, Q);
        else __hip_atomic_store(hdst, Q, __ATOMIC_RELAXED, __HIP_MEMORY_SCOPE_AGENT);

        // ---- poison own word of slot (tt-2)&7 (safe per certification invariant) ----
        {
            const int slot_p = (tt + 6) & 7;
            unsigned long long* pp = hex64 + ((size_t)(slot_p * 2 + dir) * 16 + bg) * 1024
                                   + rowr * 64 + colg;
            if (FAST) st1_sc0(pp, SENT);
            else __hip_atomic_store(pp, SENT, __ATOMIC_RELAXED, __HIP_MEMORY_SCOPE_AGENT);
        }

        // ---- outputs, off the critical path ----
        if (out_f) {
            size_t ob = (size_t)(t * 256 + m0 + quad * 4) * 512 + dir * 256
                      + cg * 64 + wave * 16 + ln15;
#pragma unroll
            for (int r = 0; r < 4; ++r) out_f[ob + (size_t)r * 512] = hv[r];
        } else {
            size_t ob = (size_t)(t * 256 + m0 + rowr) * 512 + dir * 256
                      + cg * 64 + wave * 16 + (ln15 >> 2) * 4;
            *(unsigned long long*)&out_bf[ob] = Q;
        }
    };

    for (int tt = 0; tt < 160; tt += 2) { step(tt, xvA, xvB); step(tt + 1, xvB, xvA); }
}

__global__ __launch_bounds__(256, 1) void lstm_scan7(
    const unsigned short* __restrict__ xg,
    const unsigned short* __restrict__ whh_f,
    const unsigned short* __restrict__ whh_r,
    unsigned short* __restrict__ out_bf,
    float* __restrict__ out_f,
    unsigned short* __restrict__ hexg,
    unsigned long long* __restrict__ sync)   // [128] canary u64 | [128] SA int | [128] R int
{
    const int gid = blockIdx.x & 31;
    const int cg = blockIdx.x >> 5;
    const int dir = gid & 1, bg = gid >> 1;
    const unsigned short* __restrict__ whh = dir ? whh_r : whh_f;
    unsigned long long* hex64 = (unsigned long long*)hexg;

    // ---- mechanism handshake: does sc0 exchange actually work for this group? ----
    __shared__ int s_fast;
    if (threadIdx.x == 0) {
        unsigned long long* can = sync;            // [128] u64, init ~0
        int* SA = (int*)(sync + 128);              // [128] int, init -1
        int* RR = SA + 128;                        // [128] int, init -1
        const int b = blockIdx.x;
        const unsigned long long M1 = 0x1111111111111111ull, M2 = 0x2222222222222222ull;
        int ok = 1;
        // phase A: establish sc0 visibility AND prime any (non-bypassed) caches
        st1_sc0(&can[b], M1);
        {
            int lim = 1 << 14;
            for (int p = 0; p < 4; ++p) {
                unsigned long long v;
                do { v = ld1_sc0(&can[gid + 32 * p]); } while (v != M1 && --lim > 0);
                if (v != M1) ok = 0;
            }
        }
        // agent-scope sync: all members finished phase A before any phase-B store
        __hip_atomic_store(&SA[b], 1, __ATOMIC_RELAXED, __HIP_MEMORY_SCOPE_AGENT);
        {
            int lim = 1 << 20;
            for (int p = 0; p < 4; ++p) {
                int v;
                do { v = __hip_atomic_load(&SA[gid + 32 * p], __ATOMIC_RELAXED, __HIP_MEMORY_SCOPE_AGENT); }
                while (v != 1 && --lim > 0);
                if (v != 1) ok = 0;
            }
        }
        // phase B: must OBSERVE A CHANGE through the sc0 path (stale-L1 detector)
        st1_sc0(&can[b], M2);
        {
            int lim = 1 << 14;
            for (int p = 0; p < 4; ++p) {
                unsigned long long v;
                do { v = ld1_sc0(&can[gid + 32 * p]); } while (v != M2 && --lim > 0);
                if (v != M2) ok = 0;
            }
        }
        // group-consistent verdict via proven agent ops (no mixed mode possible)
        __hip_atomic_store(&RR[b], ok, __ATOMIC_RELAXED, __HIP_MEMORY_SCOPE_AGENT);
        int fast = 1;
        {
            int lim = 1 << 20;
            for (int p = 0; p < 4; ++p) {
                int v;
                do { v = __hip_atomic_load(&RR[gid + 32 * p], __ATOMIC_RELAXED, __HIP_MEMORY_SCOPE_AGENT); }
                while (v == -1 && --lim > 0);
                fast &= (v == 1);
            }
        }
        s_fast = fast;
    }
    __syncthreads();
    if (s_fast) scan_loop<true>(xg, whh, out_bf, out_f, hex64, dir, bg, cg);
    else        scan_loop<false>(xg, whh, out_bf, out_f, hex64, dir, bg, cg);
}

// ---------------- host-side launch -----------------------------------------------
extern "C" void kernel_launch(void* const* d_in, const int* in_sizes, int n_in,
                              void* d_out, int out_size, void* d_ws, size_t ws_size,
                              hipStream_t stream) {
    const float* x = (const float*)d_in[0];
    float* out = (float*)d_out;
    char* ws = (char*)d_ws;

    // workspace layout (bytes, 256-aligned)
    unsigned short* xbf   = (unsigned short*)(ws + 0);            // 40960x512 bf16 = 41,943,040
    unsigned short* wcat0 = (unsigned short*)(ws + 41943040LL);   // 2048x512 bf16 (dead after GEMM L0)
    unsigned short* wcat1 = (unsigned short*)(ws + 44040192LL);   // 2048x512 bf16
    unsigned short* whh0f = (unsigned short*)(ws + 46137344LL);   // 4 x 1024x256 bf16
    unsigned short* whh0r = whh0f + 262144;
    unsigned short* whh1f = whh0f + 524288;
    unsigned short* whh1r = whh0f + 786432;
    float* bias0          = (float*)(ws + 48234496LL);            // 2048 f32
    float* bias1          = (float*)(ws + 48242688LL);            // 2048 f32
    unsigned short* xgbuf = (unsigned short*)(ws + 48250880LL);   // 40960x2048 bf16 = 167,772,160
    unsigned long long* syncb = (unsigned long long*)(ws + 216023040LL);  // 2 KB
    unsigned short* hexg  = wcat0;                                // 2 MB ring, reuses wcat0 slot
    unsigned short* h0b   = xbf;  // reuse: xbf dead after GEMM L0 (kernel-boundary coherence)

    // ---- prep: converts + bias combine ----
    f2bf_kernel<<<20480, 256, 0, stream>>>(x, xbf, 5242880);
    f2bf_kernel<<<512, 256, 0, stream>>>((const float*)d_in[1], wcat0, 131072);
    f2bf_kernel<<<512, 256, 0, stream>>>((const float*)d_in[5], wcat0 + 524288, 131072);
    f2bf_kernel<<<512, 256, 0, stream>>>((const float*)d_in[9], wcat1, 131072);
    f2bf_kernel<<<512, 256, 0, stream>>>((const float*)d_in[13], wcat1 + 524288, 131072);
    f2bf_kernel<<<256, 256, 0, stream>>>((const float*)d_in[2], whh0f, 65536);
    f2bf_kernel<<<256, 256, 0, stream>>>((const float*)d_in[6], whh0r, 65536);
    f2bf_kernel<<<256, 256, 0, stream>>>((const float*)d_in[10], whh1f, 65536);
    f2bf_kernel<<<256, 256, 0, stream>>>((const float*)d_in[14], whh1r, 65536);
    bias_comb_kernel<<<8, 256, 0, stream>>>((const float*)d_in[3], (const float*)d_in[4],
                                            (const float*)d_in[7], (const float*)d_in[8], bias0);
    bias_comb_kernel<<<8, 256, 0, stream>>>((const float*)d_in[11], (const float*)d_in[12],
                                            (const float*)d_in[15], (const float*)d_in[16], bias1);

    dim3 gg(16, 320);  // N/128 x M/128
    // ---- layer 0 ----
    gemm_bt_bias<<<gg, 256, 0, stream>>>(xbf, wcat0, bias0, xgbuf, 40960, 2048, 512);
    // ring init: slots 0-6 sentinel (0xFF bytes), slot 7 zeros (h_{-1} = 0)
    hipMemsetAsync(hexg, 0xFF, 2097152, stream);
    hipMemsetAsync((char*)hexg + 7 * 262144, 0, 262144, stream);
    hipMemsetAsync(syncb, 0xFF, 2048, stream);   // fresh handshake per dispatch
    lstm_scan7<<<128, 256, 0, stream>>>(xgbuf, whh0f, whh0r, h0b, nullptr, hexg, syncb);
    // ---- layer 1 ----
    gemm_bt_bias<<<gg, 256, 0, stream>>>(h0b, wcat1, bias1, xgbuf, 40960, 2048, 512);
    hipMemsetAsync(hexg, 0xFF, 2097152, stream);
    hipMemsetAsync((char*)hexg + 7 * 262144, 0, 262144, stream);
    hipMemsetAsync(syncb, 0xFF, 2048, stream);
    lstm_scan7<<<128, 256, 0, stream>>>(xgbuf, whh1f, whh1r, nullptr, out, hexg, syncb);
}

// Round 5
// 1530.398 us; speedup vs baseline: 3.5230x; 3.5230x over previous
//
#include <hip/hip_runtime.h>
#include <stdint.h>

typedef __attribute__((ext_vector_type(8))) short bf16x8;
typedef __attribute__((ext_vector_type(4))) float f32x4;

__device__ __forceinline__ float bf2f(unsigned short u) {
    union { unsigned int u32; float f; } v; v.u32 = ((unsigned int)u) << 16; return v.f;
}
__device__ __forceinline__ unsigned short f2bf(float f) {
    union { float f; unsigned int u32; } v; v.f = f;
    unsigned int r = v.u32 + 0x7FFFu + ((v.u32 >> 16) & 1u);
    return (unsigned short)(r >> 16);
}
__device__ __forceinline__ float sigm(float x) { return 1.f / (1.f + __expf(-x)); }
__device__ __forceinline__ float tanh_fast(float x) {
    float ax = fabsf(x);
    float e = __expf(-2.f * ax);
    float t = (1.f - e) / (1.f + e);
    return copysignf(t, x);
}

// ---------------- fp32 -> bf16 convert (n4 = count of float4 groups) -------------
__global__ void f2bf_kernel(const float* __restrict__ src, unsigned short* __restrict__ dst, int n4) {
    int i = blockIdx.x * blockDim.x + threadIdx.x;
    if (i >= n4) return;
    float4 v = ((const float4*)src)[i];
    ushort4 o;
    o.x = f2bf(v.x); o.y = f2bf(v.y); o.z = f2bf(v.z); o.w = f2bf(v.w);
    ((ushort4*)dst)[i] = o;
}

// ---------------- combined bias: [2048] = fwd(bih+bhh) | rev(bih+bhh) ------------
__global__ void bias_comb_kernel(const float* __restrict__ bif, const float* __restrict__ bhf,
                                 const float* __restrict__ bir, const float* __restrict__ bhr,
                                 float* __restrict__ out) {
    int n = blockIdx.x * blockDim.x + threadIdx.x;
    if (n >= 2048) return;
    out[n] = (n < 1024) ? (bif[n] + bhf[n]) : (bir[n - 1024] + bhr[n - 1024]);
}

// ---------------- GEMM: C[m,n](bf16) = sum_k A[m,k]*B[n,k] + bias[n] -------------
__global__ __launch_bounds__(256, 2) void gemm_bt_bias(
    const unsigned short* __restrict__ A, const unsigned short* __restrict__ B,
    const float* __restrict__ bias, unsigned short* __restrict__ C,
    int M, int N, int K) {
    const int bn0 = blockIdx.x * 128;
    const int bm0 = blockIdx.y * 128;
    const int tid = threadIdx.x;
    const int wave = tid >> 6, lane = tid & 63;
    const int ln15 = lane & 15, quad = lane >> 4;
    const int wr = wave >> 1, wc = wave & 1;

    __shared__ __align__(16) unsigned short At[128 * 72];
    __shared__ __align__(16) unsigned short Bt[128 * 72];

    f32x4 acc[4][4] = {};

    for (int ko = 0; ko < K; ko += 64) {
#pragma unroll
        for (int i = 0; i < 4; ++i) {
            int chunk = tid + i * 256;
            int row = chunk >> 3, cc = chunk & 7;
            *(bf16x8*)&At[row * 72 + cc * 8] = *(const bf16x8*)&A[(size_t)(bm0 + row) * K + ko + cc * 8];
            *(bf16x8*)&Bt[row * 72 + cc * 8] = *(const bf16x8*)&B[(size_t)(bn0 + row) * K + ko + cc * 8];
        }
        __syncthreads();
#pragma unroll
        for (int kk = 0; kk < 2; ++kk) {
            bf16x8 a[4], b[4];
#pragma unroll
            for (int f = 0; f < 4; ++f) {
                a[f] = *(const bf16x8*)&At[(wr * 64 + f * 16 + ln15) * 72 + kk * 32 + quad * 8];
                b[f] = *(const bf16x8*)&Bt[(wc * 64 + f * 16 + ln15) * 72 + kk * 32 + quad * 8];
            }
#pragma unroll
            for (int fi = 0; fi < 4; ++fi)
#pragma unroll
                for (int fj = 0; fj < 4; ++fj)
                    acc[fi][fj] = __builtin_amdgcn_mfma_f32_16x16x32_bf16(a[fi], b[fj], acc[fi][fj], 0, 0, 0);
        }
        __syncthreads();
    }
#pragma unroll
    for (int fi = 0; fi < 4; ++fi) {
        int row = bm0 + wr * 64 + fi * 16 + quad * 4;
#pragma unroll
        for (int fj = 0; fj < 4; ++fj) {
            int col = bn0 + wc * 64 + fj * 16 + ln15;
            float bv = bias[col];
#pragma unroll
            for (int r = 0; r < 4; ++r)
                C[(size_t)(row + r) * N + col] = f2bf(acc[fi][fj][r] + bv);
        }
    }
}

// ================= persistent LSTM scan v8: v4 protocol + v7 datapath ============
// 128 WGs: gid = b&31 (group: dir=gid&1, bg=gid>>1), cg = b>>5 (64 hidden cols).
// Ring: hexg[2 slots][2 dir][16 bg][16 rows][64 colgroups] u64 (4x bf16), zeroed.
// Protocol (v4's proven counter scheme, flags instead of fetch_add):
//   publish h (agent store, all threads) -> __syncthreads (drains vmcnt(0) for
//   every thread before s_barrier => all h stores at LLC) -> tid0 stores
//   flag[gid][tt][cg]=1. Consumer tid0 spins on the 4 flags of (tt-1) (ONE
//   cacheline, one thread polling -- light LLC traffic), then __syncthreads
//   broadcasts; af loads (agent) then see published h.
// 2-slot safety: WG X writes slot tt&1 only after flags[tt-1]==1,1,1,1, which
// certifies all group members finished step tt-1, i.e. finished CONSUMING
// h_{tt-2} -- the very data in slot tt&1. No poison needed.
// Datapath (v7-validated): wave <-> 16-col block, MFMA N-tile <-> gate; all 4
// gates land thread-local (no LDS bounce, no extra barrier); publish words are
// rebuilt row-major by an in-register 4x4 bf16 transpose (2x shfl_xor).
__global__ __launch_bounds__(256, 1) void lstm_scan8(
    const unsigned short* __restrict__ xg,      // [T*B, 2048] bf16
    const unsigned short* __restrict__ whh_f,   // [1024,256] bf16
    const unsigned short* __restrict__ whh_r,   // [1024,256] bf16
    unsigned short* __restrict__ out_bf,        // [T,B,512] bf16 (layer0) or null
    float* __restrict__ out_f,                  // [T,B,512] f32 (layer1) or null
    unsigned short* __restrict__ hexg,          // 512 KB ring (zeroed)
    int* __restrict__ flags)                    // [32][160][4] int (zeroed)
{
    const int gid = blockIdx.x & 31;
    const int cg = blockIdx.x >> 5;
    const int dir = gid & 1, bg = gid >> 1;
    const int m0 = bg * 16;
    const int tid = threadIdx.x;
    const int wave = tid >> 6, lane = tid & 63;
    const int ln15 = lane & 15, quad = lane >> 4;
    const int rowr = quad * 4 + (ln15 & 3);                 // batch-local row this lane publishes
    const int colg = cg * 16 + wave * 4 + (ln15 >> 2);      // colgroup (hidden col / 4)
    const unsigned short* __restrict__ whh = dir ? whh_r : whh_f;
    const unsigned long long M16 = 0x0000FFFF0000FFFFull;
    unsigned long long* hex64 = (unsigned long long*)hexg;
    int* fgrp = flags + gid * 160 * 4;

    // ---- one-time: Whh fragments, gate-per-N-tile (N-tile g = gate g) ----
    bf16x8 Bfr[32];
#pragma unroll
    for (int kb = 0; kb < 8; ++kb)
#pragma unroll
        for (int g = 0; g < 4; ++g)
            Bfr[kb * 4 + g] = *(const bf16x8*)&whh[
                (size_t)(g * 256 + cg * 64 + wave * 16 + ln15) * 256 + kb * 32 + quad * 8];

    float c[4] = {0.f, 0.f, 0.f, 0.f};
    const unsigned short* xbase = xg + (size_t)(m0 + quad * 4) * 2048
                                     + dir * 1024 + cg * 64 + wave * 16 + ln15;

    unsigned short xvA[16], xvB[16];
    {   // prefetch xg for tt = 0
        const int t0 = dir ? 159 : 0;
        const unsigned short* xr = xbase + (size_t)t0 * 256 * 2048;
#pragma unroll
        for (int g = 0; g < 4; ++g)
#pragma unroll
            for (int r = 0; r < 4; ++r)
                xvA[g * 4 + r] = xr[(size_t)r * 2048 + g * 256];
    }

    auto step = [&](int tt, unsigned short (&xu)[16], unsigned short (&xp)[16]) {
        const int t = dir ? (159 - tt) : tt;

        // ---- wait for all 4 group WGs to have published h_{t-1} (tid0 only) ----
        if (tt > 0) {
            if (tid == 0) {
                const int* fp = fgrp + (tt - 1) * 4;
                int lim = 1 << 22;
                for (;;) {
                    int a0 = __hip_atomic_load(fp + 0, __ATOMIC_RELAXED, __HIP_MEMORY_SCOPE_AGENT);
                    int a1 = __hip_atomic_load(fp + 1, __ATOMIC_RELAXED, __HIP_MEMORY_SCOPE_AGENT);
                    int a2 = __hip_atomic_load(fp + 2, __ATOMIC_RELAXED, __HIP_MEMORY_SCOPE_AGENT);
                    int a3 = __hip_atomic_load(fp + 3, __ATOMIC_RELAXED, __HIP_MEMORY_SCOPE_AGENT);
                    if ((a0 & a1 & a2 & a3) || !--lim) break;
                }
            }
            __syncthreads();
        }

        // ---- af h-loads FIRST (critical path); fine-grained vmcnt lets MFMA
        //      wait only on these, not on the xg prefetch issued after ----
        const int slot_r = (tt + 1) & 1;   // (tt-1)&1
        unsigned long long* hsrc = hex64 + ((size_t)(slot_r * 2 + dir) * 16 + bg) * 1024
                                 + ln15 * 64 + quad * 2;
        unsigned long long w[16];
#pragma unroll
        for (int kb = 0; kb < 8; ++kb) {
            w[kb * 2]     = __hip_atomic_load(hsrc + kb * 8,     __ATOMIC_RELAXED, __HIP_MEMORY_SCOPE_AGENT);
            w[kb * 2 + 1] = __hip_atomic_load(hsrc + kb * 8 + 1, __ATOMIC_RELAXED, __HIP_MEMORY_SCOPE_AGENT);
        }

        // ---- xg prefetch for NEXT step (latency hides under MFMA+act) ----
        {
            const int ttn = (tt < 159) ? tt + 1 : tt;
            const int tn = dir ? (159 - ttn) : ttn;
            const unsigned short* xr = xbase + (size_t)tn * 256 * 2048;
#pragma unroll
            for (int g = 0; g < 4; ++g)
#pragma unroll
                for (int r = 0; r < 4; ++r)
                    xp[g * 4 + r] = xr[(size_t)r * 2048 + g * 256];
        }

        // ---- recurrent GEMM: 32 MFMAs, acc starts at 0 (xg added at activation) ----
        bf16x8 af[8];
#pragma unroll
        for (int kb = 0; kb < 8; ++kb) {
            union { unsigned long long u[2]; bf16x8 v; } tm;
            tm.u[0] = w[kb * 2]; tm.u[1] = w[kb * 2 + 1];
            af[kb] = tm.v;
        }
        f32x4 acc[4] = {};
#pragma unroll
        for (int kb = 0; kb < 8; ++kb)
#pragma unroll
            for (int g = 0; g < 4; ++g)
                acc[g] = __builtin_amdgcn_mfma_f32_16x16x32_bf16(af[kb], Bfr[kb * 4 + g], acc[g], 0, 0, 0);

        // ---- activations + cell update: all 4 gates thread-local ----
        float hv[4];
#pragma unroll
        for (int r = 0; r < 4; ++r) {
            float iv = sigm(acc[0][r] + bf2f(xu[0 + r]));
            float fv = sigm(acc[1][r] + bf2f(xu[4 + r]));
            float gv = tanh_fast(acc[2][r] + bf2f(xu[8 + r]));
            float ov = sigm(acc[3][r] + bf2f(xu[12 + r]));
            float cn = fv * c[r] + iv * gv;
            c[r] = cn;
            hv[r] = ov * tanh_fast(cn);
        }

        // ---- pack (col-major) + in-register 4x4 bf16 transpose -> row-major ----
        unsigned long long P = (unsigned long long)f2bf(hv[0])
                             | ((unsigned long long)f2bf(hv[1]) << 16)
                             | ((unsigned long long)f2bf(hv[2]) << 32)
                             | ((unsigned long long)f2bf(hv[3]) << 48);
        unsigned long long X = __shfl_xor(P, 2);
        unsigned long long Nn = (ln15 & 2) ? ((X >> 32) | (P & 0xFFFFFFFF00000000ull))
                                           : ((P & 0x00000000FFFFFFFFull) | (X << 32));
        unsigned long long Y = __shfl_xor(Nn, 1);
        unsigned long long Q = (ln15 & 1) ? (((Y >> 16) & M16) | (((Nn >> 16) & M16) << 16))
                                          : ((Nn & M16) | ((Y & M16) << 16));

        // ---- publish h_t ----
        unsigned long long* hdst = hex64 + ((size_t)((tt & 1) * 2 + dir) * 16 + bg) * 1024
                                 + rowr * 64 + colg;
        __hip_atomic_store(hdst, Q, __ATOMIC_RELAXED, __HIP_MEMORY_SCOPE_AGENT);

        // ---- certification: __syncthreads drains vmcnt(0) for EVERY thread
        //      before s_barrier => all h stores are at the coherence point ----
        __syncthreads();
        if (tid == 0)
            __hip_atomic_store(fgrp + tt * 4 + cg, 1, __ATOMIC_RELAXED, __HIP_MEMORY_SCOPE_AGENT);

        // ---- outputs AFTER the arrival signal -> off the critical path ----
        if (out_f) {
            size_t ob = (size_t)(t * 256 + m0 + quad * 4) * 512 + dir * 256
                      + cg * 64 + wave * 16 + ln15;
#pragma unroll
            for (int r = 0; r < 4; ++r) out_f[ob + (size_t)r * 512] = hv[r];
        } else {
            size_t ob = (size_t)(t * 256 + m0 + rowr) * 512 + dir * 256
                      + cg * 64 + wave * 16 + (ln15 >> 2) * 4;
            *(unsigned long long*)&out_bf[ob] = Q;
        }
    };

    for (int tt = 0; tt < 160; tt += 2) { step(tt, xvA, xvB); step(tt + 1, xvB, xvA); }
}

// ---------------- host-side launch -----------------------------------------------
extern "C" void kernel_launch(void* const* d_in, const int* in_sizes, int n_in,
                              void* d_out, int out_size, void* d_ws, size_t ws_size,
                              hipStream_t stream) {
    const float* x = (const float*)d_in[0];
    float* out = (float*)d_out;
    char* ws = (char*)d_ws;

    // workspace layout (bytes, 256-aligned)
    unsigned short* xbf   = (unsigned short*)(ws + 0);            // 40960x512 bf16 = 41,943,040
    unsigned short* wcat0 = (unsigned short*)(ws + 41943040LL);   // 2048x512 bf16 (dead after GEMM L0)
    unsigned short* wcat1 = (unsigned short*)(ws + 44040192LL);   // 2048x512 bf16
    unsigned short* whh0f = (unsigned short*)(ws + 46137344LL);   // 4 x 1024x256 bf16
    unsigned short* whh0r = whh0f + 262144;
    unsigned short* whh1f = whh0f + 524288;
    unsigned short* whh1r = whh0f + 786432;
    float* bias0          = (float*)(ws + 48234496LL);            // 2048 f32
    float* bias1          = (float*)(ws + 48242688LL);            // 2048 f32
    unsigned short* xgbuf = (unsigned short*)(ws + 48250880LL);   // 40960x2048 bf16 = 167,772,160
    int* flagbuf          = (int*)(ws + 216023040LL);             // 32*160*4*4 = 81,920 B
    unsigned short* hexg  = wcat0;                                // 512 KB ring, reuses wcat0 slot
    unsigned short* h0b   = xbf;  // reuse: xbf dead after GEMM L0 (kernel-boundary coherence)

    // ---- prep: converts + bias combine ----
    f2bf_kernel<<<20480, 256, 0, stream>>>(x, xbf, 5242880);
    f2bf_kernel<<<512, 256, 0, stream>>>((const float*)d_in[1], wcat0, 131072);
    f2bf_kernel<<<512, 256, 0, stream>>>((const float*)d_in[5], wcat0 + 524288, 131072);
    f2bf_kernel<<<512, 256, 0, stream>>>((const float*)d_in[9], wcat1, 131072);
    f2bf_kernel<<<512, 256, 0, stream>>>((const float*)d_in[13], wcat1 + 524288, 131072);
    f2bf_kernel<<<256, 256, 0, stream>>>((const float*)d_in[2], whh0f, 65536);
    f2bf_kernel<<<256, 256, 0, stream>>>((const float*)d_in[6], whh0r, 65536);
    f2bf_kernel<<<256, 256, 0, stream>>>((const float*)d_in[10], whh1f, 65536);
    f2bf_kernel<<<256, 256, 0, stream>>>((const float*)d_in[14], whh1r, 65536);
    bias_comb_kernel<<<8, 256, 0, stream>>>((const float*)d_in[3], (const float*)d_in[4],
                                            (const float*)d_in[7], (const float*)d_in[8], bias0);
    bias_comb_kernel<<<8, 256, 0, stream>>>((const float*)d_in[11], (const float*)d_in[12],
                                            (const float*)d_in[15], (const float*)d_in[16], bias1);

    dim3 gg(16, 320);  // N/128 x M/128
    // ---- layer 0 ----
    gemm_bt_bias<<<gg, 256, 0, stream>>>(xbf, wcat0, bias0, xgbuf, 40960, 2048, 512);
    hipMemsetAsync(hexg, 0, 524288, stream);        // ring zeros (h_{-1} = 0)
    hipMemsetAsync(flagbuf, 0, 81920, stream);      // flags clear
    lstm_scan8<<<128, 256, 0, stream>>>(xgbuf, whh0f, whh0r, h0b, nullptr, hexg, flagbuf);
    // ---- layer 1 ----
    gemm_bt_bias<<<gg, 256, 0, stream>>>(h0b, wcat1, bias1, xgbuf, 40960, 2048, 512);
    hipMemsetAsync(hexg, 0, 524288, stream);
    hipMemsetAsync(flagbuf, 0, 81920, stream);
    lstm_scan8<<<128, 256, 0, stream>>>(xgbuf, whh1f, whh1r, nullptr, out, hexg, flagbuf);
}